// Round 1
// baseline (1225.954 us; speedup 1.0000x reference)
//
#include <hip/hip_runtime.h>

#define B_   8
#define C_   256
#define T_   2048
#define NQ   8
#define BINS 1024
#define NROWS (B_ * T_)          // 16384

#define BM 128
#define BN 64
#define BK 16

// ---------------- kernel 1: c2[code] = sum_c cb[code][c]^2 in fp64 ----------
__global__ __launch_bounds__(256)
void c2_kernel(const float* __restrict__ cb, double* __restrict__ c2) {
    int w    = threadIdx.x >> 6;            // wave in block (0..3)
    int lane = threadIdx.x & 63;
    int code = blockIdx.x * 4 + w;          // 8192 codes, grid = 2048
    const float* row = cb + (size_t)code * C_;
    double s = 0.0;
    #pragma unroll
    for (int i = 0; i < C_ / 64; ++i) {
        double v = (double)row[lane + i * 64];
        s += v * v;
    }
    #pragma unroll
    for (int off = 32; off; off >>= 1) s += __shfl_down(s, off, 64);
    if (lane == 0) c2[code] = s;
}

// order-preserving double -> u64 map (monotone increasing)
static __device__ __forceinline__ unsigned long long mapd(double d) {
    unsigned long long u = (unsigned long long)__double_as_longlong(d);
    return (u & 0x8000000000000000ull) ? ~u : (u | 0x8000000000000000ull);
}

// ------------- kernel 2: fused distance GEMM + argmin per (row, q) ----------
// grid = (NROWS/BM) * NQ = 128*8 = 1024 blocks, 256 threads
__global__ __launch_bounds__(256, 2)
void dist_kernel(const float* __restrict__ x, const float* __restrict__ cb,
                 const double* __restrict__ c2, float* __restrict__ idx_f,
                 int* __restrict__ idx_i) {
    __shared__ float As[BK][BM];                       // 8 KB
    __shared__ float Bs[BK][BN];                       // 4 KB
    __shared__ unsigned long long red[BM][17];         // 17.4 KB (padded)

    int blk = blockIdx.x;
    int q   = blk & 7;
    int nb  = blk >> 3;
    int n0  = nb * BM;
    int b   = n0 / T_;
    int tb  = n0 % T_;                                  // BM | T_, same b per block
    int tid = threadIdx.x;
    int tx  = tid & 15;                                 // code dim (16)
    int ty  = tid >> 4;                                 // row dim (16)

    unsigned long long bestKey[8];
    #pragma unroll
    for (int i = 0; i < 8; ++i) bestKey[i] = 0xFFFFFFFFFFFFFFFFull;

    // A staging: thread -> (k = tid>>5 and +8, m = (tid&31)*4)
    int a_k = tid >> 5;
    int a_m = (tid & 31) << 2;
    const float* xb = x + (size_t)b * C_ * T_ + tb;     // x[b][c][tb + m]

    // B staging: thread -> (code = tid>>2, k = (tid&3)*4)
    int b_c = tid >> 2;
    int b_k = (tid & 3) << 2;
    const float* cbq = cb + (size_t)q * BINS * C_;

    for (int chunk = 0; chunk < BINS / BN; ++chunk) {
        int c0 = chunk * BN;
        double acc2[8][4];
        #pragma unroll
        for (int i = 0; i < 8; ++i)
            #pragma unroll
            for (int j = 0; j < 4; ++j) acc2[i][j] = 0.0;

        for (int kb = 0; kb < C_ / BK; ++kb) {
            int k0 = kb * BK;
            __syncthreads();
            {   // stage A (x rows): coalesced over t
                float4 v0 = *(const float4*)(xb + (size_t)(k0 + a_k) * T_ + a_m);
                float4 v1 = *(const float4*)(xb + (size_t)(k0 + a_k + 8) * T_ + a_m);
                *(float4*)&As[a_k][a_m]     = v0;
                *(float4*)&As[a_k + 8][a_m] = v1;
            }
            {   // stage B (codebook rows), transpose to [k][code]
                float4 v = *(const float4*)(cbq + (size_t)(c0 + b_c) * C_ + k0 + b_k);
                Bs[b_k + 0][b_c] = v.x;
                Bs[b_k + 1][b_c] = v.y;
                Bs[b_k + 2][b_c] = v.z;
                Bs[b_k + 3][b_c] = v.w;
            }
            __syncthreads();

            float acc[8][4];
            #pragma unroll
            for (int i = 0; i < 8; ++i)
                #pragma unroll
                for (int j = 0; j < 4; ++j) acc[i][j] = 0.f;

            #pragma unroll
            for (int k = 0; k < BK; ++k) {
                float4 a0 = *(const float4*)&As[k][ty * 8];
                float4 a1 = *(const float4*)&As[k][ty * 8 + 4];
                float4 bv = *(const float4*)&Bs[k][tx * 4];
                float av[8] = {a0.x, a0.y, a0.z, a0.w, a1.x, a1.y, a1.z, a1.w};
                float bw[4] = {bv.x, bv.y, bv.z, bv.w};
                #pragma unroll
                for (int i = 0; i < 8; ++i)
                    #pragma unroll
                    for (int j = 0; j < 4; ++j) acc[i][j] = fmaf(av[i], bw[j], acc[i][j]);
            }
            // fold fp32 sub-accumulators into fp64 (bounds accumulation error ~4e-6)
            #pragma unroll
            for (int i = 0; i < 8; ++i)
                #pragma unroll
                for (int j = 0; j < 4; ++j) acc2[i][j] += (double)acc[i][j];
        }

        // scores for this chunk: score = c2 - 2*xc (x2 is row-constant, irrelevant)
        #pragma unroll
        for (int j = 0; j < 4; ++j) {
            int code = c0 + tx * 4 + j;
            double cc = c2[(size_t)q * BINS + code];
            #pragma unroll
            for (int i = 0; i < 8; ++i) {
                double score = cc - 2.0 * acc2[i][j];
                // chop 10 low mantissa bits, pack bin index; ties -> lower index
                unsigned long long key =
                    (mapd(score) & 0xFFFFFFFFFFFFFC00ull) | (unsigned long long)code;
                if (key < bestKey[i]) bestKey[i] = key;
            }
        }
    }

    __syncthreads();
    #pragma unroll
    for (int i = 0; i < 8; ++i) red[ty * 8 + i][tx] = bestKey[i];
    __syncthreads();

    if (tid < BM) {
        unsigned long long best = red[tid][0];
        #pragma unroll
        for (int j = 1; j < 16; ++j) {
            unsigned long long k2 = red[tid][j];
            if (k2 < best) best = k2;
        }
        int bin = (int)(best & 1023ull);
        int n   = n0 + tid;
        idx_f[(size_t)n * NQ + q] = (float)bin;
        idx_i[(size_t)n * NQ + q] = bin;
    }
}

// ------------- kernel 3: gather-sum, q_ste output, loss ---------------------
// grid = B_ * (T_/16) = 1024 blocks, 256 threads; 16 t's per block
__global__ __launch_bounds__(256)
void gather_kernel(const float* __restrict__ x, const float* __restrict__ cb,
                   const int* __restrict__ idx_i, float* __restrict__ out,
                   float* __restrict__ loss) {
    __shared__ float ql[C_][17];   // [c][t_local], padded: 17.4 KB

    int blk = blockIdx.x;
    int b   = blk >> 7;
    int t0  = (blk & 127) << 4;
    int tid = threadIdx.x;

    {   // phase A: thread = c, loop t_local; codebook reads coalesced over c
        int c = tid;
        for (int nl = 0; nl < 16; ++nl) {
            int n = b * T_ + t0 + nl;
            float acc = 0.f;
            #pragma unroll
            for (int qq = 0; qq < NQ; ++qq) {
                int id = idx_i[(size_t)n * NQ + qq];
                acc += cb[((size_t)qq * BINS + id) * C_ + c];
            }
            ql[c][nl] = acc;
        }
    }
    __syncthreads();

    // phase B: (tx = t_local, ty = c group), coalesced x read + out write
    int tx = tid & 15, ty = tid >> 4;
    float lsum = 0.f;
    for (int cg = 0; cg < 16; ++cg) {
        int c = cg * 16 + ty;
        size_t off = ((size_t)b * C_ + c) * T_ + t0 + tx;
        float qv = ql[c][tx];
        float xv = x[off];
        out[off] = qv;                   // q_ste == quantized numerically
        float d  = qv - xv;
        lsum += d * d;
    }
    #pragma unroll
    for (int off = 32; off; off >>= 1) lsum += __shfl_down(lsum, off, 64);
    if ((tid & 63) == 0)
        atomicAdd(loss, lsum * (2.0f / (float)(B_ * C_ * T_)));
}

extern "C" void kernel_launch(void* const* d_in, const int* in_sizes, int n_in,
                              void* d_out, int out_size, void* d_ws, size_t ws_size,
                              hipStream_t stream) {
    const float* x  = (const float*)d_in[0];
    const float* cb = (const float*)d_in[1];

    float* out    = (float*)d_out;
    float* idx_f  = out + (size_t)B_ * C_ * T_;            // 4194304
    float* loss   = idx_f + (size_t)NROWS * NQ;            // +131072

    double* c2    = (double*)d_ws;                         // 64 KB
    int*    idx_i = (int*)((char*)d_ws + (size_t)NQ * BINS * sizeof(double));

    hipMemsetAsync(loss, 0, sizeof(float), stream);
    c2_kernel<<<2048, 256, 0, stream>>>(cb, c2);
    dist_kernel<<<(NROWS / BM) * NQ, 256, 0, stream>>>(x, cb, c2, idx_f, idx_i);
    gather_kernel<<<B_ * (T_ / 16), 256, 0, stream>>>(x, cb, idx_i, out, loss);
}